// Round 7
// baseline (928.511 us; speedup 1.0000x reference)
//
#include <hip/hip_runtime.h>
#include <hip/hip_fp16.h>

#define N_NODES 100000
#define KK 5
#define CC 16
#define EE 3200000
#define NXCC 8

#define EPB 2560             // edges per block
#define NBLK 6250            // 16,000,000 / EPB
#define BLKS_PER_K 1250      // EE / EPB (exact -> each block is single-k)

typedef int   int4v   __attribute__((ext_vector_type(4)));
typedef int   int2v   __attribute__((ext_vector_type(2)));
typedef float float4v __attribute__((ext_vector_type(4)));
typedef float float2v __attribute__((ext_vector_type(2)));

__device__ __forceinline__ int xcc_id() {
    int x;
    asm volatile("s_getreg_b32 %0, hwreg(HW_REG_XCC_ID)" : "=s"(x));
    return x & (NXCC - 1);
}

// Kernel 1: Zt[k*N + n] = sum_c X[n,c] * h[c,k]  (fp32; 2 MB total -> the
// WHOLE Z table is L2-resident in every XCD during the edge pass)
__global__ void compute_z_kernel(const float* __restrict__ X,
                                 const float* __restrict__ h,
                                 float* __restrict__ Zt) {
    int n = blockIdx.x * blockDim.x + threadIdx.x;
    if (n >= N_NODES) return;
    const float4* Xr = (const float4*)(X + (size_t)n * CC);
    float4 x0 = Xr[0], x1 = Xr[1], x2 = Xr[2], x3 = Xr[3];
    float xv[CC] = {x0.x, x0.y, x0.z, x0.w, x1.x, x1.y, x1.z, x1.w,
                    x2.x, x2.y, x2.z, x2.w, x3.x, x3.y, x3.z, x3.w};
#pragma unroll
    for (int k = 0; k < KK; ++k) {
        float acc = 0.0f;
#pragma unroll
        for (int c = 0; c < CC; ++c) acc += xv[c] * h[c * KK + k];
        Zt[k * N_NODES + n] = acc;
    }
}

// R7 ARCHITECTURE PIVOT: single-pass far-atomic. Six rounds of evidence say
// the 3-kernel binned pipeline has a ~345us floor distributed across chunk-
// serial barrier chains + an accum kernel pinned at ~scatter duration + the
// 128 MB binned round-trip. This kernel eliminates ALL of it:
//   - 192 MB edge stream, coalesced, NONTEMPORAL (evict-first: keeps the
//     2 MB Zt hot in L2), no barriers, no LDS, full wave parallelism
//   - 16M gathers from L2-resident Zt
//   - 16M fire-and-forget global_atomic_add_f32 into the XCD-LOCAL replica
//     (8 x 400 KB, L2-resident, zero cross-XCD atomic traffic)
// Layout: block b owns edges [b*2560, (b+1)*2560) -- single k per block
// (EE = 1250*2560 exactly). 10 edges/thread: all gathers issued, then all
// atomics (atomics have no return -> no dependent stalls).
__global__ __launch_bounds__(256)
void edge_kernel(const int* __restrict__ rows,
                 const int* __restrict__ cols,
                 const float* __restrict__ vals,
                 const float* __restrict__ Zt,
                 float* __restrict__ yrep) {
    int tid  = threadIdx.x;
    int b    = blockIdx.x;
    int base = b * EPB;
    int k    = b / BLKS_PER_K;                        // block-uniform (SGPR)
    const float* Zk = Zt + (size_t)k * N_NODES;
    float* yr = yrep + (size_t)xcc_id() * N_NODES;

    int e0 = base + tid * 4;
    int e1 = e0 + 1024;
    int e2 = base + 2048 + tid * 2;

    // ---- edge stream: 9 nontemporal vector loads in flight ----
    int4v   r0 = __builtin_nontemporal_load((const int4v*)(rows + e0));
    int4v   c0 = __builtin_nontemporal_load((const int4v*)(cols + e0));
    float4v v0 = __builtin_nontemporal_load((const float4v*)(vals + e0));
    int4v   r1 = __builtin_nontemporal_load((const int4v*)(rows + e1));
    int4v   c1 = __builtin_nontemporal_load((const int4v*)(cols + e1));
    float4v v1 = __builtin_nontemporal_load((const float4v*)(vals + e1));
    int2v   r2 = __builtin_nontemporal_load((const int2v*)(rows + e2));
    int2v   c2 = __builtin_nontemporal_load((const int2v*)(cols + e2));
    float2v v2 = __builtin_nontemporal_load((const float2v*)(vals + e2));

    // ---- all 10 gathers (L2-resident Zt) issued before any consumer ----
    float z[10];
    z[0] = Zk[c0[0]]; z[1] = Zk[c0[1]]; z[2] = Zk[c0[2]]; z[3] = Zk[c0[3]];
    z[4] = Zk[c1[0]]; z[5] = Zk[c1[1]]; z[6] = Zk[c1[2]]; z[7] = Zk[c1[3]];
    z[8] = Zk[c2[0]]; z[9] = Zk[c2[1]];

    // ---- 10 fire-and-forget atomics into the XCD-local replica ----
    unsafeAtomicAdd(&yr[r0[0]], v0[0] * z[0]);
    unsafeAtomicAdd(&yr[r0[1]], v0[1] * z[1]);
    unsafeAtomicAdd(&yr[r0[2]], v0[2] * z[2]);
    unsafeAtomicAdd(&yr[r0[3]], v0[3] * z[3]);
    unsafeAtomicAdd(&yr[r1[0]], v1[0] * z[4]);
    unsafeAtomicAdd(&yr[r1[1]], v1[1] * z[5]);
    unsafeAtomicAdd(&yr[r1[2]], v1[2] * z[6]);
    unsafeAtomicAdd(&yr[r1[3]], v1[3] * z[7]);
    unsafeAtomicAdd(&yr[r2[0]], v2[0] * z[8]);
    unsafeAtomicAdd(&yr[r2[1]], v2[1] * z[9]);
}

// y[n] = sum over the 8 XCD replicas
__global__ void reduce8_kernel(const float* __restrict__ yrep,
                               float* __restrict__ y) {
    int n = blockIdx.x * blockDim.x + threadIdx.x;
    if (n >= N_NODES) return;
    float acc = 0.0f;
#pragma unroll
    for (int r = 0; r < NXCC; ++r) acc += yrep[(size_t)r * N_NODES + n];
    y[n] = acc;
}

extern "C" void kernel_launch(void* const* d_in, const int* in_sizes, int n_in,
                              void* d_out, int out_size, void* d_ws, size_t ws_size,
                              hipStream_t stream) {
    const float* X    = (const float*)d_in[0];
    const int*   rows = (const int*)  d_in[1];
    const int*   cols = (const int*)  d_in[2];
    const float* vals = (const float*)d_in[3];
    const float* h    = (const float*)d_in[4];
    float* y = (float*)d_out;

    char* ws = (char*)d_ws;
    float* Zt   = (float*)ws;                              // 2,000,000 B
    float* yrep = (float*)(ws + 2000000);                  // 3,200,000 B
    // total need: 5.2 MB (ws was >= 143 MB in all prior rounds)

    {   // Z = X @ h  (Zt layout [k][n])
        int threads = 256;
        int blocks  = (N_NODES + threads - 1) / threads;
        compute_z_kernel<<<blocks, threads, 0, stream>>>(X, h, Zt);
    }

    hipMemsetAsync(yrep, 0, (size_t)NXCC * N_NODES * sizeof(float), stream);

    edge_kernel<<<NBLK, 256, 0, stream>>>(rows, cols, vals, Zt, yrep);

    {
        int threads = 256;
        int blocks  = (N_NODES + threads - 1) / threads;
        reduce8_kernel<<<blocks, threads, 0, stream>>>(yrep, y);
    }
}

// Round 9
// 383.663 us; speedup vs baseline: 2.4201x; 2.4201x over previous
//
#include <hip/hip_runtime.h>
#include <hip/hip_fp16.h>

#define N_NODES 100000
#define KK 5
#define CC 16
#define EE 3200000
#define NXCC 8

#define NB 16                // row buckets
#define ROWS_PB 6250         // N_NODES / NB
#define WCAP 384             // entries per (chunk,bucket) window (+3.7 sigma)
#define WPAD 385             // LDS staging stride
#define SLICES 16            // accum slices per bucket -> NB*SLICES = 256 blocks
#define CHUNK 5120           // edges per scatter chunk
#define NCHUNK 3125          // 3125 * 5120 = 16,000,000
#define BLK_PER_K 625        // EE / CHUNK
#define SGRID 256            // persistent blocks (1/CU)
#define SN_MAIN 65536        // LDS-cached Z-slice nodes (fp16, 128 KB)
#define STAG ((size_t)NB * WPAD * 4)             // 24,640 B staging
#define ACCUM_LDS (ROWS_PB * 4 + 200 * 4)        // 25,800 B

typedef unsigned int uint2v __attribute__((ext_vector_type(2)));

__device__ __forceinline__ int xcc_id() {
    int x;
    asm volatile("s_getreg_b32 %0, hwreg(HW_REG_XCC_ID)" : "=s"(x));
    return x & (NXCC - 1);
}

// ---------- dispatch 1: Zh = fp16(X @ h); zero y, spill, barrier ctr -------
__global__ void z_kernel(const float* __restrict__ X,
                         const float* __restrict__ h,
                         __half* __restrict__ Zh,
                         float* __restrict__ spill,
                         float* __restrict__ y,
                         unsigned int* __restrict__ barrier_ctr) {
    int gtid = blockIdx.x * blockDim.x + threadIdx.x;
    if (gtid == 0) *barrier_ctr = 0;                   // re-arm per graph replay
    if (gtid >= N_NODES) return;
    const float4* Xr = (const float4*)(X + (size_t)gtid * CC);
    float4 x0 = Xr[0], x1 = Xr[1], x2 = Xr[2], x3 = Xr[3];
    float xv[CC] = {x0.x, x0.y, x0.z, x0.w, x1.x, x1.y, x1.z, x1.w,
                    x2.x, x2.y, x2.z, x2.w, x3.x, x3.y, x3.z, x3.w};
#pragma unroll
    for (int k = 0; k < KK; ++k) {
        float acc = 0.0f;
#pragma unroll
        for (int c = 0; c < CC; ++c) acc += xv[c] * h[c * KK + k];
        Zh[k * N_NODES + gtid] = __float2half_rn(acc);
    }
    spill[gtid] = 0.0f;
    y[gtid]     = 0.0f;
}

// ---------- device-scope software barrier (capture-safe, no coop API) ------
// syncthreads drains each thread's stores (compiler emits vmcnt(0) before
// s_barrier); tid0: release fence (L2 writeback) -> agent atomic ticket ->
// acquire spin -> acquire fence (invalidate); syncthreads releases the block.
// Counter is monotone: stale profiler replays fall through, never deadlock.
__device__ __forceinline__ void grid_barrier(unsigned int* ctr, int tid) {
    __syncthreads();
    if (tid == 0) {
        __threadfence();
        __hip_atomic_fetch_add(ctr, 1u, __ATOMIC_ACQ_REL, __HIP_MEMORY_SCOPE_AGENT);
        while (__hip_atomic_load(ctr, __ATOMIC_ACQUIRE, __HIP_MEMORY_SCOPE_AGENT)
               < (unsigned)SGRID)
            __builtin_amdgcn_s_sleep(32);
        __threadfence();
    }
    __syncthreads();
}

// ---------- phase A: scatter (R5-verbatim 126us structure) -----------------
template<int SN>
__device__ __forceinline__ void scatter_phase(const int* __restrict__ rows,
                                              const int* __restrict__ cols,
                                              const float* __restrict__ vals,
                                              const __half* Zh,
                                              unsigned int* binned,
                                              int* counts, float* spill,
                                              char* dynlds, int bid, int tid) {
    __shared__ int lcnt[NB];
    __half*       zsl = (__half*)dynlds;                          // SN*2 B
    unsigned int* buf = (unsigned int*)(dynlds + (size_t)SN * 2); // STAG B
    int w0b = (int)(((long long)NCHUNK * bid) / SGRID);
    int w1b = (int)(((long long)NCHUNK * (bid + 1)) / SGRID);

    int klast = -1;
    for (int w = w0b; w < w1b; ++w) {
        int k = w / BLK_PER_K;                             // block-uniform
        const __half* Zk_h = Zh + (size_t)k * N_NODES;
        if (SN > 0 && k != klast) {
            __syncthreads();                               // prior chunk done with zsl
            const float4* zsrc = (const float4*)Zk_h;      // 16B-aligned
            float4*       zdst = (float4*)dynlds;
#pragma unroll
            for (int i = 0; i < SN / 4096; ++i)
                zdst[tid + i * 512] = zsrc[tid + i * 512];
            klast = k;
            __syncthreads();
        }
        if (tid < NB) lcnt[tid] = 0;
        __syncthreads();

        int cbase = w * CHUNK;
        int e0 = cbase + tid * 4;
        int e1 = cbase + 2048 + tid * 4;
        int e2 = cbase + 4096 + tid * 2;
        int4   r0 = *(const int4*)(rows + e0);
        int4   c0 = *(const int4*)(cols + e0);
        float4 v0 = *(const float4*)(vals + e0);
        int4   r1 = *(const int4*)(rows + e1);
        int4   c1 = *(const int4*)(cols + e1);
        float4 v1 = *(const float4*)(vals + e1);
        int2   r2 = *(const int2*)(rows + e2);
        int2   c2 = *(const int2*)(cols + e2);
        float2 v2 = *(const float2*)(vals + e2);

        int   cix[10] = {c0.x, c0.y, c0.z, c0.w, c1.x, c1.y, c1.z, c1.w, c2.x, c2.y};
        int   rr[10]  = {r0.x, r0.y, r0.z, r0.w, r1.x, r1.y, r1.z, r1.w, r2.x, r2.y};
        float vv[10]  = {v0.x, v0.y, v0.z, v0.w, v1.x, v1.y, v1.z, v1.w, v2.x, v2.y};

        float z[10];
#pragma unroll
        for (int i = 0; i < 10; ++i) {
            unsigned c = (unsigned)cix[i];
            __half hz;
            if (SN > 0 && c < (unsigned)SN) hz = zsl[c];
            else                            hz = Zk_h[c];
            z[i] = __half2float(hz);
        }

        int pos[10];
#pragma unroll
        for (int i = 0; i < 10; ++i) {
            int b = rr[i] / ROWS_PB;                       // magic-mul
            pos[i] = atomicAdd(&lcnt[b], 1);
        }

#pragma unroll
        for (int i = 0; i < 10; ++i) {
            int b = rr[i] / ROWS_PB;
            float cb = vv[i] * z[i];
            int p = pos[i];
            if (p < WCAP) {
                unsigned int packed =
                    ((unsigned)(rr[i] - b * ROWS_PB) << 16) |
                    (unsigned)__half_as_ushort(__float2half_rn(cb));
                buf[b * WPAD + p] = packed;
            } else {
                unsafeAtomicAdd(&spill[rr[i]], cb);        // exact, ~never taken
            }
        }
        __syncthreads();

        unsigned int* wbase = binned + (size_t)w * WCAP;
#pragma unroll 1
        for (int b = 0; b < NB; ++b) {
            int cnt = min(lcnt[b], WCAP);                  // wave-uniform
            if (tid < cnt)
                wbase[(size_t)b * ((size_t)NCHUNK * WCAP) + tid] = buf[b * WPAD + tid];
        }
        if (tid < NB) counts[w * NB + tid] = min(lcnt[tid], WCAP);
        __syncthreads();                                   // buf/lcnt reuse
    }
}

// ---------- phase B: accum; bucket b slice s; spill fold; atomic y ---------
__device__ __forceinline__ void accum_phase(const unsigned int* binned,
                                            const int* counts,
                                            const float* spill, float* y,
                                            char* dynlds, int bid, int tid) {
    float* acc  = (float*)dynlds;                          // 25,000 B
    int*   cnts = (int*)(dynlds + ROWS_PB * 4);            // <= 196 ints
    int b = bid >> 4;
    int s = bid & (SLICES - 1);
    int wlo = (NCHUNK * s) / SLICES;
    int whi = (NCHUNK * (s + 1)) / SLICES;
    int nw  = whi - wlo;                                   // <= 196
    for (int i = tid; i < ROWS_PB; i += 512) acc[i] = 0.0f;
    for (int i = tid; i < nw; i += 512) cnts[i] = counts[(wlo + i) * NB + b];
    __syncthreads();

    const unsigned int* bbase = binned + (size_t)b * ((size_t)NCHUNK * WCAP);
    int t = tid & 255, half = tid >> 8;
    for (int w0 = wlo; w0 < whi; w0 += 16) {
        uint2v e[8];
        int ok0[8], ok1[8];
#pragma unroll
        for (int j = 0; j < 8; ++j) {
            int w = w0 + 2 * j + half;
            int cnt = (w < whi) ? cnts[w - wlo] : 0;
            ok0[j] = 2 * t < cnt;
            ok1[j] = 2 * t + 1 < cnt;
            const uint2v* src = (const uint2v*)(bbase + (size_t)w * WCAP);
            uint2v ez = {0u, 0u};
            e[j] = ok0[j] ? src[t] : ez;                   // exec-masked 8B load
        }
#pragma unroll
        for (int j = 0; j < 8; ++j) {
            if (ok0[j])
                atomicAdd(&acc[e[j][0] >> 16],
                          __half2float(__ushort_as_half((unsigned short)(e[j][0] & 0xFFFFu))));
            if (ok1[j])
                atomicAdd(&acc[e[j][1] >> 16],
                          __half2float(__ushort_as_half((unsigned short)(e[j][1] & 0xFFFFu))));
        }
    }
    __syncthreads();
    int nbase = b * ROWS_PB;
    if (s == 0)
        for (int i = tid; i < ROWS_PB; i += 512) acc[i] += spill[nbase + i];
    for (int i = tid; i < ROWS_PB; i += 512)
        unsafeAtomicAdd(&y[nbase + i], acc[i]);            // coalesced, 16 contenders
}

// ---------- dispatch 2: scatter -> sw grid barrier -> accum ----------------
template<int SN>
__global__ __launch_bounds__(512, 1)
void fused_sa_kernel(const int* __restrict__ rows, const int* __restrict__ cols,
                     const float* __restrict__ vals, const __half* __restrict__ Zh,
                     unsigned int* __restrict__ binned, int* __restrict__ counts,
                     float* __restrict__ spill, float* __restrict__ y,
                     unsigned int* __restrict__ barrier_ctr) {
    extern __shared__ char dynlds[];
    int tid = threadIdx.x, bid = blockIdx.x;
    scatter_phase<SN>(rows, cols, vals, Zh, binned, counts, spill, dynlds, bid, tid);
    grid_barrier(barrier_ctr, tid);
    accum_phase(binned, counts, spill, y, dynlds, bid, tid);
}

// ---------- tiny-workspace fallback: far-atomic path -----------------------
__global__ void edge_atomic_kernel(const int* __restrict__ rows,
                                   const int* __restrict__ cols,
                                   const float* __restrict__ vals,
                                   const __half* __restrict__ Zh,
                                   float* __restrict__ yrep) {
    int t = blockIdx.x * blockDim.x + threadIdx.x;
    int base = t * 4;
    if (base >= KK * EE) return;
    int k = base / EE;
    const __half* Zk = Zh + (size_t)k * N_NODES;
    float* yr = yrep + (size_t)xcc_id() * N_NODES;
    int4 r = *(const int4*)(rows + base);
    int4 c = *(const int4*)(cols + base);
    float4 v = *(const float4*)(vals + base);
    unsafeAtomicAdd(&yr[r.x], v.x * __half2float(Zk[c.x]));
    unsafeAtomicAdd(&yr[r.y], v.y * __half2float(Zk[c.y]));
    unsafeAtomicAdd(&yr[r.z], v.z * __half2float(Zk[c.z]));
    unsafeAtomicAdd(&yr[r.w], v.w * __half2float(Zk[c.w]));
}

__global__ void reduce8_kernel(const float* __restrict__ yrep, float* __restrict__ y) {
    int n = blockIdx.x * blockDim.x + threadIdx.x;
    if (n >= N_NODES) return;
    float acc = 0.0f;
#pragma unroll
    for (int r = 0; r < NXCC; ++r) acc += yrep[(size_t)r * N_NODES + n];
    y[n] = acc;
}

extern "C" void kernel_launch(void* const* d_in, const int* in_sizes, int n_in,
                              void* d_out, int out_size, void* d_ws, size_t ws_size,
                              hipStream_t stream) {
    const float* X    = (const float*)d_in[0];
    const int*   rows = (const int*)  d_in[1];
    const int*   cols = (const int*)  d_in[2];
    const float* vals = (const float*)d_in[3];
    const float* h    = (const float*)d_in[4];
    float* y = (float*)d_out;

    char* ws = (char*)d_ws;
    __half*       Zh     = (__half*)ws;                    //  1,000,000 B
    int*          counts = (int*)(ws + 1000000);           //    200,000 B
    float*        spill  = (float*)(ws + 1200000);         //    400,000 B
    unsigned int* bar    = (unsigned int*)(ws + 1600000);  //         64 B
    unsigned int* binned = (unsigned int*)(ws + 1600064);  // 76,800,000 B
    size_t need = 1600064 + (size_t)NCHUNK * NB * WCAP * 4;   // ~78.4 MB

    if (ws_size >= need) {
        // one-time capture-legal probe: can the 153 KB-LDS variant launch?
        static int g_sn = -1;
        static size_t g_dyn = 0;
        if (g_sn < 0) {
            g_sn = 0;
            g_dyn = (STAG > (size_t)ACCUM_LDS) ? STAG : (size_t)ACCUM_LDS;
            size_t dynM = (size_t)SN_MAIN * 2 + STAG;      // 155,712 B
            hipFuncSetAttribute((const void*)fused_sa_kernel<SN_MAIN>,
                                hipFuncAttributeMaxDynamicSharedMemorySize, (int)dynM);
            int nb = 0;
            if (hipOccupancyMaxActiveBlocksPerMultiprocessor(
                    &nb, fused_sa_kernel<SN_MAIN>, 512, dynM) == hipSuccess && nb >= 1) {
                g_sn = SN_MAIN;
                g_dyn = dynM;
            }
        }

        z_kernel<<<(N_NODES + 511) / 512, 512, 0, stream>>>(X, h, Zh, spill, y, bar);

        if (g_sn == SN_MAIN)
            fused_sa_kernel<SN_MAIN><<<SGRID, 512, g_dyn, stream>>>(
                rows, cols, vals, Zh, binned, counts, spill, y, bar);
        else
            fused_sa_kernel<0><<<SGRID, 512, g_dyn, stream>>>(
                rows, cols, vals, Zh, binned, counts, spill, y, bar);
    } else {
        // tiny-workspace fallback (needs ~4.6 MB)
        float* spillF = (float*)(ws + 1000000);
        float* yrep   = (float*)(ws + 1400000);            // 3,200,000 B
        unsigned int* barF = (unsigned int*)(ws + 1000000 + 399936);
        z_kernel<<<(N_NODES + 511) / 512, 512, 0, stream>>>(X, h, Zh, spillF, y, barF);
        hipMemsetAsync(yrep, 0, (size_t)NXCC * N_NODES * sizeof(float), stream);
        {
            int threads = 256;
            int blocks = ((KK * EE) / 4 + threads - 1) / threads;
            edge_atomic_kernel<<<blocks, threads, 0, stream>>>(rows, cols, vals, Zh, yrep);
        }
        {
            int threads = 256;
            int blocks  = (N_NODES + threads - 1) / threads;
            reduce8_kernel<<<blocks, threads, 0, stream>>>(yrep, y);
        }
    }
}

// Round 10
// 329.343 us; speedup vs baseline: 2.8193x; 1.1649x over previous
//
#include <hip/hip_runtime.h>
#include <hip/hip_fp16.h>

#define N_NODES 100000
#define KK 5
#define CC 16
#define EE 3200000
#define NXCC 8

#define NB 16                // row buckets
#define ROWS_PB 6250         // N_NODES / NB
#define WCAP 384             // entries per (chunk,bucket) window (+3.7 sigma)
#define WPAD 385             // LDS staging stride
#define BPB 64               // accum blocks per bucket (16*64 = 1024 blocks)
#define CHUNK 5120           // edges per scatter chunk
#define NCHUNK 3125          // 3125 * 5120 = 16,000,000
#define BLK_PER_K 625        // EE / CHUNK
#define SGRID 256            // persistent scatter blocks (1/CU)
#define STHREADS 1024        // R10: 16 waves/CU (was 512 -> 8); slice regime is
                             // latency-starved at 8 waves (R3's null was no-slice)

typedef unsigned int uint2v __attribute__((ext_vector_type(2)));

__device__ __forceinline__ int xcc_id() {
    int x;
    asm volatile("s_getreg_b32 %0, hwreg(HW_REG_XCC_ID)" : "=s"(x));
    return x & (NXCC - 1);
}

// Kernel 1: Zt[k*N + n] (fp32, fallback) and Zh[k*N + n] (fp16, scatter)
__global__ void compute_z_kernel(const float* __restrict__ X,
                                 const float* __restrict__ h,
                                 float* __restrict__ Zt,
                                 __half* __restrict__ Zh) {
    int n = blockIdx.x * blockDim.x + threadIdx.x;
    if (n >= N_NODES) return;
    const float4* Xr = (const float4*)(X + (size_t)n * CC);
    float4 x0 = Xr[0], x1 = Xr[1], x2 = Xr[2], x3 = Xr[3];
    float xv[CC] = {x0.x, x0.y, x0.z, x0.w, x1.x, x1.y, x1.z, x1.w,
                    x2.x, x2.y, x2.z, x2.w, x3.x, x3.y, x3.z, x3.w};
#pragma unroll
    for (int k = 0; k < KK; ++k) {
        float acc = 0.0f;
#pragma unroll
        for (int c = 0; c < CC; ++c) acc += xv[c] * h[c * KK + k];
        Zt[k * N_NODES + n] = acc;
        Zh[k * N_NODES + n] = __float2half_rn(acc);
    }
}

// Phase A (R10): R5 structure (LDS fp16 Z-slice, 65% gather hits, windowed
// staging, coalesced bucket-major flush) at 1024 threads/block. Ledger after
// R9's fusion experiment: total = ~120us FIXED harness overhead + scatter 126
// + accum ~90 + ~10 misc. R5 ran 1 block x 8 waves/CU (21% occ); the per-chunk
// critical path (9 dependent L3 loads + gather chain + 2 barriers, x12.2
// serial chunks) is under-hidden at 8 waves. 1024 thr -> 16 waves, same LDS,
// same structure. If null: ~5cyc/edge is an issue-rate floor, not latency.
template<int SN>
__global__ __launch_bounds__(STHREADS, 1)
void scatter_lds_kernel(const int* __restrict__ rows,
                        const int* __restrict__ cols,
                        const float* __restrict__ vals,
                        const __half* __restrict__ Zh,
                        unsigned int* __restrict__ binned,
                        int* __restrict__ counts,
                        float* __restrict__ spill) {
    extern __shared__ char dynlds[];
    __half*       zsl = (__half*)dynlds;                          // SN*2 B
    unsigned int* buf = (unsigned int*)(dynlds + (size_t)SN * 2); // NB*WPAD*4
    __shared__ int lcnt[NB];
    int tid = threadIdx.x;
    int bid = blockIdx.x;
    int w0 = (int)(((long long)NCHUNK * bid) / SGRID);
    int w1 = (int)(((long long)NCHUNK * (bid + 1)) / SGRID);

    int klast = -1;
    for (int w = w0; w < w1; ++w) {
        int k = w / BLK_PER_K;                             // block-uniform
        const __half* Zk_h = Zh + (size_t)k * N_NODES;
        if (SN > 0 && k != klast) {
            __syncthreads();                               // prior chunk done with zsl
            const float4* zsrc = (const float4*)Zk_h;      // 16B-aligned
            float4*       zdst = (float4*)dynlds;
#pragma unroll
            for (int i = 0; i < SN / 8192; ++i)            // SN/8 float4s, 1024 thr
                zdst[tid + i * 1024] = zsrc[tid + i * 1024];
            klast = k;
            __syncthreads();
        }
        if (tid < NB) lcnt[tid] = 0;
        __syncthreads();

        int cbase = w * CHUNK;
        // ---- inputs: 5 edges/thread (one int4 group + one scalar) ----
        int e0 = cbase + tid * 4;
        int e4 = cbase + 4096 + tid;
        int4   r0 = *(const int4*)(rows + e0);
        int4   c0 = *(const int4*)(cols + e0);
        float4 v0 = *(const float4*)(vals + e0);
        int    r1 = rows[e4];
        int    c1 = cols[e4];
        float  v1 = vals[e4];

        int   cix[5] = {c0.x, c0.y, c0.z, c0.w, c1};
        int   rr[5]  = {r0.x, r0.y, r0.z, r0.w, r1};
        float vv[5]  = {v0.x, v0.y, v0.z, v0.w, v1};

        // ---- gathers: LDS slice hit (~65%) or residual L2/L3 request ----
        float z[5];
#pragma unroll
        for (int i = 0; i < 5; ++i) {
            unsigned c = (unsigned)cix[i];
            __half hz;
            if (SN > 0 && c < (unsigned)SN) hz = zsl[c];
            else                            hz = Zk_h[c];
            z[i] = __half2float(hz);
        }

        // ---- LDS position allocation (overlaps residual gathers) ----
        int pos[5];
#pragma unroll
        for (int i = 0; i < 5; ++i) {
            int b = rr[i] / ROWS_PB;                       // magic-mul
            pos[i] = atomicAdd(&lcnt[b], 1);
        }

        // ---- pack + stage ----
#pragma unroll
        for (int i = 0; i < 5; ++i) {
            int b = rr[i] / ROWS_PB;
            float cb = vv[i] * z[i];
            int p = pos[i];
            if (p < WCAP) {
                unsigned int packed =
                    ((unsigned)(rr[i] - b * ROWS_PB) << 16) |
                    (unsigned)__half_as_ushort(__float2half_rn(cb));
                buf[b * WPAD + p] = packed;
            } else {
                unsafeAtomicAdd(&spill[rr[i]], cb);        // exact, ~never taken
            }
        }
        __syncthreads();

        // ---- coalesced flush, bucket-major global layout [b][w][WCAP] ----
        unsigned int* wbase = binned + (size_t)w * WCAP;
#pragma unroll 1
        for (int b = 0; b < NB; ++b) {
            int cnt = min(lcnt[b], WCAP);                  // wave-uniform
            if (tid < cnt)
                wbase[(size_t)b * ((size_t)NCHUNK * WCAP) + tid] = buf[b * WPAD + tid];
        }
        if (tid < NB) counts[w * NB + tid] = min(lcnt[tid], WCAP);
        __syncthreads();                                   // buf/lcnt reuse next chunk
    }
}

// Phase B (R5-verbatim, control): counts in LDS; uint2 payload, two windows
// concurrent (tid split 2x256), 16 windows/outer iter, 8 loads in flight.
__global__ __launch_bounds__(512, 2)
void accum_kernel(const unsigned int* __restrict__ binned,
                  const int* __restrict__ counts,
                  float* __restrict__ partials) {
    __shared__ float acc[ROWS_PB];                    // 25 KB
    __shared__ int cnts[56];                          // whi-wlo <= 49
    int b = blockIdx.x / BPB;
    int s = blockIdx.x % BPB;
    int tid = threadIdx.x;
    int wlo = (NCHUNK * s) / BPB;
    int whi = (NCHUNK * (s + 1)) / BPB;
    for (int i = tid; i < ROWS_PB; i += 512) acc[i] = 0.0f;
    if (tid < whi - wlo) cnts[tid] = counts[(wlo + tid) * NB + b];
    __syncthreads();

    const unsigned int* bbase = binned + (size_t)b * ((size_t)NCHUNK * WCAP);
    int t    = tid & 255;                             // entry-pair index
    int half = tid >> 8;                              // which window of the pair
    for (int w0 = wlo; w0 < whi; w0 += 16) {
        uint2v e[8];
        int ok0[8], ok1[8];
#pragma unroll
        for (int j = 0; j < 8; ++j) {
            int w = w0 + 2 * j + half;
            int cnt = (w < whi) ? cnts[w - wlo] : 0;
            ok0[j] = 2 * t < cnt;
            ok1[j] = 2 * t + 1 < cnt;
            const uint2v* src = (const uint2v*)(bbase + (size_t)w * WCAP);
            uint2v ez = {0u, 0u};
            e[j] = ok0[j] ? src[t] : ez;              // exec-masked 8B load
        }
#pragma unroll
        for (int j = 0; j < 8; ++j) {
            if (ok0[j])
                atomicAdd(&acc[e[j][0] >> 16],
                          __half2float(__ushort_as_half((unsigned short)(e[j][0] & 0xFFFFu))));
            if (ok1[j])
                atomicAdd(&acc[e[j][1] >> 16],
                          __half2float(__ushort_as_half((unsigned short)(e[j][1] & 0xFFFFu))));
        }
    }
    __syncthreads();
    float* dst = partials + (size_t)blockIdx.x * ROWS_PB;
    for (int i = tid; i < ROWS_PB; i += 512) dst[i] = acc[i];
}

// y[n] = spill[n] + sum over BPB partial slices of n's bucket
__global__ void reduce_kernel(const float* __restrict__ partials,
                              const float* __restrict__ spill,
                              float* __restrict__ y) {
    int n = blockIdx.x * blockDim.x + threadIdx.x;
    if (n >= N_NODES) return;
    int b = n / ROWS_PB, loc = n - b * ROWS_PB;
    const float* p = partials + (size_t)(b * BPB) * ROWS_PB + loc;
    float acc = spill[n];
#pragma unroll 8
    for (int s = 0; s < BPB; ++s) acc += p[(size_t)s * ROWS_PB];
    y[n] = acc;
}

// ---------- fallback path: far-atomic scatter, used if ws too small ----
__global__ void edge_kernel_atomic(const int* __restrict__ rows,
                                   const int* __restrict__ cols,
                                   const float* __restrict__ vals,
                                   const float* __restrict__ Zt,
                                   float* __restrict__ yrep) {
    int t = blockIdx.x * blockDim.x + threadIdx.x;
    int base = t * 4;
    if (base >= KK * EE) return;
    int k = base / EE;
    const float* Zk = Zt + (size_t)k * N_NODES;
    float* y = yrep + (size_t)xcc_id() * N_NODES;
    int4 r = *(const int4*)(rows + base);
    int4 c = *(const int4*)(cols + base);
    float4 v = *(const float4*)(vals + base);
    unsafeAtomicAdd(&y[r.x], v.x * Zk[c.x]);
    unsafeAtomicAdd(&y[r.y], v.y * Zk[c.y]);
    unsafeAtomicAdd(&y[r.z], v.z * Zk[c.z]);
    unsafeAtomicAdd(&y[r.w], v.w * Zk[c.w]);
}

__global__ void reduce8_kernel(const float* __restrict__ yrep, float* __restrict__ y) {
    int n = blockIdx.x * blockDim.x + threadIdx.x;
    if (n >= N_NODES) return;
    float acc = 0.0f;
#pragma unroll
    for (int r = 0; r < NXCC; ++r) acc += yrep[(size_t)r * N_NODES + n];
    y[n] = acc;
}

extern "C" void kernel_launch(void* const* d_in, const int* in_sizes, int n_in,
                              void* d_out, int out_size, void* d_ws, size_t ws_size,
                              hipStream_t stream) {
    const float* X    = (const float*)d_in[0];
    const int*   rows = (const int*)  d_in[1];
    const int*   cols = (const int*)  d_in[2];
    const float* vals = (const float*)d_in[3];
    const float* h    = (const float*)d_in[4];
    float* y = (float*)d_out;

    char* ws = (char*)d_ws;
    float*  Zt = (float*)ws;                                   //  2,000,000 B
    size_t zh_off      = 2000000;                              //  1,000,000 B
    size_t counts_off  = 3000000;                              //    200,000 B
    size_t spill_off   = 3200000;                              //    400,000 B
    size_t binned_off  = 3600000;
    size_t binned_sz   = (size_t)NCHUNK * NB * WCAP * 4;       //  76,800,000 B
    size_t partial_off = binned_off + binned_sz;
    size_t partial_sz  = (size_t)NB * BPB * ROWS_PB * 4;       //  25,600,000 B
    size_t need = partial_off + partial_sz;                    // ~106.0 MB
    __half* Zh = (__half*)(ws + zh_off);

    {   // Z = X @ h  (Zt layout [k][n], fp32 + fp16)
        int threads = 256;
        int blocks  = (N_NODES + threads - 1) / threads;
        compute_z_kernel<<<blocks, threads, 0, stream>>>(X, h, Zt, Zh);
    }

    if (ws_size >= need) {
        int*          counts   = (int*)(ws + counts_off);
        float*        spill    = (float*)(ws + spill_off);
        unsigned int* binned   = (unsigned int*)(ws + binned_off);
        float*        partials = (float*)(ws + partial_off);
        hipMemsetAsync(spill, 0, 400000, stream);

        // runtime probe: largest launchable Z-slice (capture-legal queries only)
        static int g_sn = -1;
        const size_t stag = (size_t)NB * WPAD * 4;             // 24,640 B
        if (g_sn < 0) {
            g_sn = 0;
            int nb = 0;
            hipFuncSetAttribute((const void*)scatter_lds_kernel<65536>,
                                hipFuncAttributeMaxDynamicSharedMemorySize,
                                (int)(65536 * 2 + stag));
            if (hipOccupancyMaxActiveBlocksPerMultiprocessor(
                    &nb, scatter_lds_kernel<65536>, STHREADS, 65536 * 2 + stag) == hipSuccess
                && nb >= 1) g_sn = 65536;
            if (g_sn == 0) {
                nb = 0;
                hipFuncSetAttribute((const void*)scatter_lds_kernel<49152>,
                                    hipFuncAttributeMaxDynamicSharedMemorySize,
                                    (int)(49152 * 2 + stag));
                if (hipOccupancyMaxActiveBlocksPerMultiprocessor(
                        &nb, scatter_lds_kernel<49152>, STHREADS, 49152 * 2 + stag) == hipSuccess
                    && nb >= 1) g_sn = 49152;
            }
            if (g_sn == 0) {
                nb = 0;
                hipFuncSetAttribute((const void*)scatter_lds_kernel<32768>,
                                    hipFuncAttributeMaxDynamicSharedMemorySize,
                                    (int)(32768 * 2 + stag));
                if (hipOccupancyMaxActiveBlocksPerMultiprocessor(
                        &nb, scatter_lds_kernel<32768>, STHREADS, 32768 * 2 + stag) == hipSuccess
                    && nb >= 1) g_sn = 32768;
            }
        }
        size_t dyn = (size_t)g_sn * 2 + stag;
        switch (g_sn) {
        case 65536:
            scatter_lds_kernel<65536><<<SGRID, STHREADS, dyn, stream>>>(
                rows, cols, vals, Zh, binned, counts, spill);
            break;
        case 49152:
            scatter_lds_kernel<49152><<<SGRID, STHREADS, dyn, stream>>>(
                rows, cols, vals, Zh, binned, counts, spill);
            break;
        case 32768:
            scatter_lds_kernel<32768><<<SGRID, STHREADS, dyn, stream>>>(
                rows, cols, vals, Zh, binned, counts, spill);
            break;
        default:
            scatter_lds_kernel<0><<<SGRID, STHREADS, dyn, stream>>>(
                rows, cols, vals, Zh, binned, counts, spill);
            break;
        }

        accum_kernel<<<NB * BPB, 512, 0, stream>>>(binned, counts, partials);
        {
            int threads = 256;
            int blocks  = (N_NODES + threads - 1) / threads;
            reduce_kernel<<<blocks, threads, 0, stream>>>(partials, spill, y);
        }
    } else {
        // fallback: far-atomic path
        float* yrep = (float*)(ws + spill_off);
        hipMemsetAsync(yrep, 0, (size_t)NXCC * N_NODES * sizeof(float), stream);
        {
            int threads = 256;
            int blocks = ((KK * EE) / 4 + threads - 1) / threads;
            edge_kernel_atomic<<<blocks, threads, 0, stream>>>(rows, cols, vals, Zt, yrep);
        }
        {
            int threads = 256;
            int blocks  = (N_NODES + threads - 1) / threads;
            reduce8_kernel<<<blocks, threads, 0, stream>>>(yrep, y);
        }
    }
}